// Round 2
// baseline (5508.294 us; speedup 1.0000x reference)
//
#include <hip/hip_runtime.h>
#include <stdint.h>

#define B_SZ 4096
#define T_SZ 64
#define ND   128
#define HID  1024
#define PO   256   // ELEMS_B = N_DIM * N_CONTROL

typedef __attribute__((ext_vector_type(8))) short bf16x8;
typedef __attribute__((ext_vector_type(4))) float f32x4;

__device__ __forceinline__ unsigned short f2bf(float x) {
  unsigned int u = __float_as_uint(x);
  u += 0x7fffu + ((u >> 16) & 1u);
  return (unsigned short)(u >> 16);
}
__device__ __forceinline__ float bf2f(unsigned short h) {
  return __uint_as_float(((unsigned int)h) << 16);
}

__device__ __forceinline__ void g2lds(const void* g, void* l) {
  __builtin_amdgcn_global_load_lds(
      (const __attribute__((address_space(1))) unsigned int*)g,
      (__attribute__((address_space(3))) unsigned int*)l, 16, 0, 0);
}

// C = (Ahi+Alo) @ (Bhi+Blo)^T, split bf16x2, fp32 accum.
// A: M x K row-major (hi/lo bf16). B: N x K row-major (pre-transposed).
// EPI 1: Z = relu(acc + bias + a0*w1r[n] + a1*w1r[HID+n]) -> split hi/lo
// EPI 2: Z = relu(acc + bias)                             -> split hi/lo
// EPI 3: fused state update: s += DT*(P[:,2n]a0 + P[:,2n+1]a1), write gen/sH/sL
template <int BM, int BN, int BK, int MT, int NT, int NWY, int EPI, int T>
__global__ __launch_bounds__(T) void gemm_split(
    const unsigned short* __restrict__ Ahi, const unsigned short* __restrict__ Alo,
    const unsigned short* __restrict__ Bhi, const unsigned short* __restrict__ Blo,
    const float* __restrict__ bias, int K, int ldc,
    const float* __restrict__ a_t, const float* __restrict__ w1r,
    unsigned short* __restrict__ Zhi, unsigned short* __restrict__ Zlo,
    float* __restrict__ s, unsigned short* __restrict__ sH,
    unsigned short* __restrict__ sL, float* __restrict__ gen, int tstep) {
  constexpr int ROWB = BK * 2;                 // bytes per tile row
  constexpr int RA = (BM * ROWB) / (T * 16);   // 16B rounds per buffer
  static_assert(BM == BN && BM * ROWB == RA * T * 16, "tile/thread mismatch");
  __shared__ __attribute__((aligned(16))) unsigned short AsH[BM * BK];
  __shared__ __attribute__((aligned(16))) unsigned short AsL[BM * BK];
  __shared__ __attribute__((aligned(16))) unsigned short BsH[BN * BK];
  __shared__ __attribute__((aligned(16))) unsigned short BsL[BN * BK];

  const int tid  = threadIdx.x;
  const int lane = tid & 63;
  const int wave = tid >> 6;
  const int wm = (wave / NWY) * (MT * 16);
  const int wn = (wave % NWY) * (NT * 16);
  const int m0 = blockIdx.x * BM;
  const int n0 = blockIdx.y * BN;
  const size_t Kb = (size_t)K * 2;

  size_t gA[RA], gB[RA];
  int lL[RA];
#pragma unroll
  for (int r = 0; r < RA; ++r) {
    int L = (r * T + tid) * 16;   // byte offset in tile; lds dest = wave base + lane*16
    int row = L / ROWB;
    int colb = L % ROWB;
    lL[r] = L;
    gA[r] = (size_t)(m0 + row) * Kb + colb;
    gB[r] = (size_t)(n0 + row) * Kb + colb;
  }

  f32x4 acc[MT][NT] = {};
  const char* Ah = (const char*)Ahi;
  const char* Al = (const char*)Alo;
  const char* Bh = (const char*)Bhi;
  const char* Bl = (const char*)Blo;
  char* asH = (char*)AsH; char* asL = (char*)AsL;
  char* bsH = (char*)BsH; char* bsL = (char*)BsL;

  const int kIt = K / BK;
  for (int it = 0; it < kIt; ++it) {
    const size_t kadd = (size_t)it * ROWB;
#pragma unroll
    for (int r = 0; r < RA; ++r) {
      g2lds(Ah + gA[r] + kadd, asH + lL[r]);
      g2lds(Al + gA[r] + kadd, asL + lL[r]);
      g2lds(Bh + gB[r] + kadd, bsH + lL[r]);
      g2lds(Bl + gB[r] + kadd, bsL + lL[r]);
    }
    __syncthreads();

#pragma unroll
    for (int ks = 0; ks < BK / 32; ++ks) {
      bf16x8 fa_h[MT], fa_l[MT], fb_h[NT], fb_l[NT];
#pragma unroll
      for (int mt = 0; mt < MT; ++mt) {
        int off = (wm + mt * 16 + (lane & 15)) * BK + ks * 32 + (lane >> 4) * 8;
        fa_h[mt] = *(const bf16x8*)&AsH[off];
        fa_l[mt] = *(const bf16x8*)&AsL[off];
      }
#pragma unroll
      for (int nt = 0; nt < NT; ++nt) {
        int off = (wn + nt * 16 + (lane & 15)) * BK + ks * 32 + (lane >> 4) * 8;
        fb_h[nt] = *(const bf16x8*)&BsH[off];
        fb_l[nt] = *(const bf16x8*)&BsL[off];
      }
#pragma unroll
      for (int mt = 0; mt < MT; ++mt)
#pragma unroll
        for (int nt = 0; nt < NT; ++nt) {
          acc[mt][nt] = __builtin_amdgcn_mfma_f32_16x16x32_bf16(fa_h[mt], fb_h[nt], acc[mt][nt], 0, 0, 0);
          acc[mt][nt] = __builtin_amdgcn_mfma_f32_16x16x32_bf16(fa_l[mt], fb_h[nt], acc[mt][nt], 0, 0, 0);
          acc[mt][nt] = __builtin_amdgcn_mfma_f32_16x16x32_bf16(fa_h[mt], fb_l[nt], acc[mt][nt], 0, 0, 0);
        }
    }
    __syncthreads();
  }

  // epilogue: C/D layout col = lane&15, row = (lane>>4)*4 + reg  [m89-verified]
#pragma unroll
  for (int mt = 0; mt < MT; ++mt) {
    const int mb = m0 + wm + mt * 16 + ((lane >> 4) << 2);
#pragma unroll
    for (int nt = 0; nt < NT; ++nt) {
      const int n = n0 + wn + nt * 16 + (lane & 15);
      const float bv = bias[n];
      if (EPI == 3) {
        const int ns = n >> 1;
#pragma unroll
        for (int r = 0; r < 4; ++r) {
          const int row = mb + r;
          float v = acc[mt][nt][r] + bv;
          float av = a_t[row * 2 + (n & 1)];
          float w = v * av * 0.1f;
          float wsum = w + __shfl_xor(w, 1);
          if (!(lane & 1)) {
            const int si = row * ND + ns;
            float sn = s[si] + wsum;
            s[si] = sn;
            unsigned short h = f2bf(sn);
            sH[si] = h;
            sL[si] = f2bf(sn - bf2f(h));
            gen[(size_t)row * ((T_SZ + 1) * ND) + (size_t)(tstep + 1) * ND + ns] = sn;
          }
        }
      } else {
        float w0 = 0.f, w1 = 0.f;
        if (EPI == 1) { w0 = w1r[n]; w1 = w1r[HID + n]; }
#pragma unroll
        for (int r = 0; r < 4; ++r) {
          float v = acc[mt][nt][r] + bv;
          if (EPI == 1) v += a_t[(mb + r) * 2] * w0 + a_t[(mb + r) * 2 + 1] * w1;
          v = fmaxf(v, 0.f);
          const size_t idx = (size_t)(mb + r) * ldc + n;
          unsigned short h = f2bf(v);
          Zhi[idx] = h;
          Zlo[idx] = f2bf(v - bf2f(h));
        }
      }
    }
  }
}

// Tiled transpose + bf16 hi/lo split: src (R x C fp32, row stride CS, cols
// [colOff, colOff+gridDim.y*32)) -> dstH/dstL as (C_sub x R) bf16.
__global__ __launch_bounds__(256) void transpose_split(
    const float* __restrict__ src, int CS, int R, int colOff,
    unsigned short* __restrict__ dH, unsigned short* __restrict__ dL) {
  __shared__ float tile[32][33];
  const int tx = threadIdx.x & 31, ty = threadIdx.x >> 5;  // ty 0..7
  const int r0 = blockIdx.x * 32;
#pragma unroll
  for (int j = 0; j < 4; ++j)
    tile[ty + j * 8][tx] =
        src[(size_t)(r0 + ty + j * 8) * CS + blockIdx.y * 32 + colOff + tx];
  __syncthreads();
#pragma unroll
  for (int j = 0; j < 4; ++j) {
    const int c = blockIdx.y * 32 + ty + j * 8;  // output row (rel col idx)
    const float v = tile[tx][ty + j * 8];
    unsigned short h = f2bf(v);
    dH[(size_t)c * R + r0 + tx] = h;
    dL[(size_t)c * R + r0 + tx] = f2bf(v - bf2f(h));
  }
}

// actions (B, T, 2) -> aT (T, B, 2), tiled transpose of float2 elements
__global__ __launch_bounds__(256) void act_transpose(
    const float2* __restrict__ acts, float2* __restrict__ aT) {
  __shared__ float2 tile[32][33];
  const int tx = threadIdx.x & 31, ty = threadIdx.x >> 5;
  const int b0 = blockIdx.x * 32, t0 = blockIdx.y * 32;
#pragma unroll
  for (int j = 0; j < 4; ++j)
    tile[ty + j * 8][tx] = acts[(size_t)(b0 + ty + j * 8) * T_SZ + t0 + tx];
  __syncthreads();
#pragma unroll
  for (int j = 0; j < 4; ++j)
    aT[(size_t)(t0 + ty + j * 8) * B_SZ + b0 + tx] = tile[tx][ty + j * 8];
}

// s0 = states[:,0,:]; split hi/lo; gen[:,0,:] = s0
__global__ __launch_bounds__(256) void init_state(
    const float* __restrict__ states, float* __restrict__ s,
    unsigned short* __restrict__ sH, unsigned short* __restrict__ sL,
    float* __restrict__ gen) {
  const int i = blockIdx.x * 256 + threadIdx.x;  // B_SZ*ND threads
  const int b = i >> 7, n = i & 127;
  const float v = states[(size_t)b * (T_SZ * ND) + n];
  s[i] = v;
  unsigned short h = f2bf(v);
  sH[i] = h;
  sL[i] = f2bf(v - bf2f(h));
  gen[(size_t)b * ((T_SZ + 1) * ND) + n] = v;
}

extern "C" void kernel_launch(void* const* d_in, const int* in_sizes, int n_in,
                              void* d_out, int out_size, void* d_ws, size_t ws_size,
                              hipStream_t stream) {
  const float* states  = (const float*)d_in[0];
  const float* actions = (const float*)d_in[1];
  const float* W1 = (const float*)d_in[2];
  const float* b1 = (const float*)d_in[3];
  const float* W2 = (const float*)d_in[4];
  const float* b2 = (const float*)d_in[5];
  const float* W3 = (const float*)d_in[6];
  const float* b3 = (const float*)d_in[7];
  float* gen = (float*)d_out;

  char* w = (char*)d_ws;
  float*          s    = (float*)(w + 0);                          // 2 MB
  unsigned short* sH   = (unsigned short*)(w + (2ull << 20));      // 1 MB
  unsigned short* sL   = (unsigned short*)(w + (3ull << 20));      // 1 MB
  unsigned short* z1H  = (unsigned short*)(w + (4ull << 20));      // 8 MB
  unsigned short* z1L  = (unsigned short*)(w + (12ull << 20));     // 8 MB
  unsigned short* z2H  = (unsigned short*)(w + (20ull << 20));     // 8 MB
  unsigned short* z2L  = (unsigned short*)(w + (28ull << 20));     // 8 MB
  float*          aT   = (float*)(w + (36ull << 20));              // 2 MB
  unsigned short* W1tH = (unsigned short*)(w + (38ull << 20));             // 256 KB
  unsigned short* W1tL = (unsigned short*)(w + (38ull << 20) + 262144);    // 256 KB
  unsigned short* W2tH = (unsigned short*)(w + (39ull << 20));             // 2 MB
  unsigned short* W2tL = (unsigned short*)(w + (41ull << 20));             // 2 MB
  unsigned short* W3tH = (unsigned short*)(w + (43ull << 20));             // 512 KB
  unsigned short* W3tL = (unsigned short*)(w + (43ull << 20) + 524288);    // 512 KB
  // total ws use: 44 MB

  transpose_split<<<dim3(4, 32), 256, 0, stream>>>(W1, 1024, 128, 0, W1tH, W1tL);
  transpose_split<<<dim3(32, 32), 256, 0, stream>>>(W2, 1024, 1024, 0, W2tH, W2tL);
  transpose_split<<<dim3(32, 8), 256, 0, stream>>>(W3, 512, 1024, 256, W3tH, W3tL);
  act_transpose<<<dim3(128, 2), 256, 0, stream>>>((const float2*)actions, (float2*)aT);
  init_state<<<2048, 256, 0, stream>>>(states, s, sH, sL, gen);

  const float* w1r = W1 + 128 * 1024;  // W1 rows 128,129 (action columns), fp32
  for (int t = 0; t < 64; ++t) {
    const float* at = aT + (size_t)t * B_SZ * 2;
    // L1: z1 = relu([s,a] @ W1 + b1)   (K=128 MFMA + exact fp32 rank-2)
    gemm_split<128, 128, 64, 2, 4, 2, 1, 512><<<dim3(32, 8), 512, 0, stream>>>(
        sH, sL, W1tH, W1tL, b1, 128, HID, at, w1r, z1H, z1L,
        nullptr, nullptr, nullptr, nullptr, 0);
    // L2: z2 = relu(z1 @ W2 + b2)
    gemm_split<128, 128, 64, 2, 4, 2, 2, 512><<<dim3(32, 8), 512, 0, stream>>>(
        z1H, z1L, W2tH, W2tL, b2, HID, HID, nullptr, nullptr, z2H, z2L,
        nullptr, nullptr, nullptr, nullptr, 0);
    // L3 + fused state update: P = z2 @ W3[:,256:] + b3[256:]; s += DT*(P·a)
    gemm_split<64, 64, 32, 2, 2, 2, 3, 256><<<dim3(64, 4), 256, 0, stream>>>(
        z2H, z2L, W3tH, W3tL, b3 + 256, HID, 0, at, nullptr, nullptr, nullptr,
        s, sH, sL, gen, t);
  }
}